// Round 10
// baseline (294.719 us; speedup 1.0000x reference)
//
#include <hip/hip_runtime.h>

#define D 128
#define N_CLS 40

// ---------------------------------------------------------------------------
// bf16 helpers (RNE)
// ---------------------------------------------------------------------------
__device__ __forceinline__ unsigned f2bf(float f) {
  unsigned u = __builtin_bit_cast(unsigned, f);
  u += 0x7fffu + ((u >> 16) & 1u);
  return u >> 16;
}
__device__ __forceinline__ float bf_lo(unsigned u) {
  return __builtin_bit_cast(float, u << 16);
}
__device__ __forceinline__ float bf_hi(unsigned u) {
  return __builtin_bit_cast(float, u & 0xffff0000u);
}

// 3-phase device-wide exclusive scan over counts[n] (n % 4 == 0).
__global__ __launch_bounds__(256) void scan_partA(
    const int* __restrict__ counts, int* __restrict__ partials, int n4) {
  __shared__ int sh[256];
  const int tid = threadIdx.x;
  const int g = blockIdx.x * 256 + tid;
  int s = 0;
  if (g < n4) {
    const int4 c = reinterpret_cast<const int4*>(counts)[g];
    s = c.x + c.y + c.z + c.w;
  }
  sh[tid] = s;
  __syncthreads();
  for (int off = 128; off > 0; off >>= 1) {
    if (tid < off) sh[tid] += sh[tid + off];
    __syncthreads();
  }
  if (tid == 0) partials[blockIdx.x] = sh[0];
}

__global__ __launch_bounds__(64) void scan_partB(
    int* __restrict__ partials, int* __restrict__ row_start, int nP,
    int n, int n_edges) {
  const int lane = threadIdx.x;
  int v = (lane < nP) ? partials[lane] : 0;
  int x = v;
  for (int off = 1; off < 64; off <<= 1) {
    int y = __shfl_up(x, off, 64);
    if (lane >= off) x += y;
  }
  if (lane < nP) partials[lane] = x - v;
  if (lane == 0) row_start[n] = n_edges;
}

__global__ __launch_bounds__(256) void scan_partC(
    int* __restrict__ counts, const int* __restrict__ partials,
    int* __restrict__ row_start, int n4) {
  __shared__ int sh[256];
  const int tid = threadIdx.x;
  const int g = blockIdx.x * 256 + tid;
  int4 c = make_int4(0, 0, 0, 0);
  if (g < n4) c = reinterpret_cast<const int4*>(counts)[g];
  const int s0 = c.x;
  const int s1 = s0 + c.y;
  const int s2 = s1 + c.z;
  const int s3 = s2 + c.w;
  sh[tid] = s3;
  __syncthreads();
  for (int off = 1; off < 256; off <<= 1) {
    int y = (tid >= off) ? sh[tid - off] : 0;
    __syncthreads();
    sh[tid] += y;
    __syncthreads();
  }
  if (g < n4) {
    const int base = partials[blockIdx.x] + sh[tid] - s3;
    const int4 rs = make_int4(base, base + s0, base + s1, base + s2);
    reinterpret_cast<int4*>(row_start)[g] = rs;
    reinterpret_cast<int4*>(counts)[g] = rs;
  }
}

__global__ __launch_bounds__(256) void fill_kernel(
    const int* __restrict__ src, const int* __restrict__ dst,
    int* __restrict__ cursor, int* __restrict__ col_idx, int n_edges) {
  int e = blockIdx.x * 256 + threadIdx.x;
  if (e < n_edges) {
    int p = atomicAdd(&cursor[dst[e]], 1);
    col_idx[p] = src[e];
  }
}

// ---------------------------------------------------------------------------
// Merged converter + degree count:
//   blocks [0, nxb):          x float4 -> packed bf16
//   blocks [nxb, nxb+nwb):    W0/W1/W2 -> bf16 (W2 padded to 48 rows)
//   blocks [nxb+nwb, ...):    counts[dst[e]]++  (edge histogram)
// ---------------------------------------------------------------------------
__global__ __launch_bounds__(256) void convert_count(
    const float4* __restrict__ x4, uint2* __restrict__ xb, int n4, int nxb,
    const float* __restrict__ W0, const float* __restrict__ W1,
    const float* __restrict__ W2, unsigned short* __restrict__ W0b,
    unsigned short* __restrict__ W1b, unsigned short* __restrict__ W2b,
    int nwb, const int* __restrict__ dst, int* __restrict__ counts,
    int n_edges) {
  if ((int)blockIdx.x < nxb) {
    int i = blockIdx.x * 256 + threadIdx.x;
    if (i < n4) {
      float4 v = x4[i];
      xb[i] = make_uint2(f2bf(v.x) | (f2bf(v.y) << 16),
                         f2bf(v.z) | (f2bf(v.w) << 16));
    }
  } else if ((int)blockIdx.x < nxb + nwb) {
    int idx = (blockIdx.x - nxb) * 256 + threadIdx.x;
    const int n0 = 128 * 128, n1 = 128 * 128, n2 = 48 * 128;
    if (idx < n0) {
      W0b[idx] = (unsigned short)f2bf(W0[idx]);
    } else if (idx < n0 + n1) {
      int i = idx - n0;
      W1b[i] = (unsigned short)f2bf(W1[i]);
    } else if (idx < n0 + n1 + n2) {
      int i = idx - n0 - n1;
      int r = i >> 7;
      W2b[i] = (r < N_CLS) ? (unsigned short)f2bf(W2[i]) : (unsigned short)0;
    }
  } else {
    int e = (blockIdx.x - nxb - nwb) * 256 + threadIdx.x;
    if (e < n_edges) atomicAdd(&counts[dst[e]], 1);
  }
}

// ---------------------------------------------------------------------------
// Gather-aggregate in bf16: out[n] = h[n] + sum_{j in row n} h[col_idx[j]]
// One wave per node. Single COALESCED index load col_idx[s+lane] covers
// deg<=64 (max deg here ~28); per-round indices come from __shfl (register
// speed). Dependent-chain = row_start -> col block -> row loads only.
// Masked 16-wide rounds; fp32 accumulation; guarded scalar tail for deg>64.
// ---------------------------------------------------------------------------
__global__ __launch_bounds__(256) void gather_bf16(
    const unsigned* __restrict__ h, const int* __restrict__ row_start,
    const int* __restrict__ col_idx, unsigned* __restrict__ out, int n_nodes) {
  int wave = (blockIdx.x * 256 + threadIdx.x) >> 6;
  int lane = threadIdx.x & 63;
  if (wave >= n_nodes) return;
  const int s = row_start[wave];
  const int e = row_start[wave + 1];
  const int deg = e - s;

  unsigned su = h[(size_t)wave * 64 + lane];  // self term
  float ax[8], ay[8];
  ax[0] = bf_lo(su); ay[0] = bf_hi(su);
#pragma unroll
  for (int i = 1; i < 8; ++i) { ax[i] = 0.f; ay[i] = 0.f; }

  if (deg > 0) {
    const int cap = (deg < 64) ? deg : 64;
    // one coalesced load: lane k holds col_idx[s + min(k, cap-1)]
    const int ci = col_idx[s + ((lane < cap) ? lane : (cap - 1))];

    for (int base = 0; base < cap; base += 16) {
      unsigned v[16];
#pragma unroll
      for (int k = 0; k < 16; ++k) {
        int idx = base + k;
        int u = __shfl(ci, (idx < cap) ? idx : (cap - 1), 64);
        unsigned vv = h[(size_t)u * 64 + lane];
        v[k] = (idx < cap) ? vv : 0u;
      }
#pragma unroll
      for (int k = 0; k < 16; ++k) {
        ax[k & 7] += bf_lo(v[k]);
        ay[k & 7] += bf_hi(v[k]);
      }
    }
    // practically-impossible tail (deg > 64), correctness only
    for (int j = s + 64; j < e; ++j) {
      unsigned v = h[(size_t)col_idx[j] * 64 + lane];
      ax[0] += bf_lo(v); ay[0] += bf_hi(v);
    }
  }

  float sx = (ax[0] + ax[1]) + (ax[2] + ax[3]) + ((ax[4] + ax[5]) + (ax[6] + ax[7]));
  float sy = (ay[0] + ay[1]) + (ay[2] + ay[3]) + ((ay[4] + ay[5]) + (ay[6] + ay[7]));
  out[(size_t)wave * 64 + lane] = f2bf(sx) | (f2bf(sy) << 16);
}

// ---------------------------------------------------------------------------
// MFMA GEMM: out[M, ncols] = act(A[M,128] @ B[NT*16,128]^T + bias)
// A, B bf16 row-major (K=128 contiguous). Block = 256 thr = 4 waves, 64 rows.
// A/B-frag: lane holds row (lane&15), k = (lane>>4)*8 + j  (16 B loads).
// C/D: col = lane&15, row = (lane>>4)*4 + reg.
// ---------------------------------------------------------------------------
typedef __attribute__((ext_vector_type(8))) short bf16x8;
typedef __attribute__((ext_vector_type(4))) float f32x4;

template <int NT, bool RELU, bool OUTBF16>
__global__ __launch_bounds__(256) void gemm_mfma(
    const unsigned short* __restrict__ A, const unsigned short* __restrict__ B,
    const float* __restrict__ bias, void* __restrict__ out, int M, int ncols) {
  const int tid = threadIdx.x;
  const int wv = tid >> 6;
  const int lane = tid & 63;
  const int m_base = blockIdx.x * 64 + wv * 16;
  const int r16 = lane & 15;
  const int quad = lane >> 4;

  const short* Ap = (const short*)A + (size_t)(m_base + r16) * D + quad * 8;
  bf16x8 af[4];
#pragma unroll
  for (int ks = 0; ks < 4; ++ks)
    af[ks] = *reinterpret_cast<const bf16x8*>(Ap + ks * 32);

  f32x4 acc[NT];
#pragma unroll
  for (int nt = 0; nt < NT; ++nt) {
    acc[nt] = (f32x4){0.f, 0.f, 0.f, 0.f};
    const short* Bp = (const short*)B + (size_t)(nt * 16 + r16) * D + quad * 8;
#pragma unroll
    for (int ks = 0; ks < 4; ++ks) {
      bf16x8 bf = *reinterpret_cast<const bf16x8*>(Bp + ks * 32);
      acc[nt] = __builtin_amdgcn_mfma_f32_16x16x32_bf16(af[ks], bf, acc[nt], 0, 0, 0);
    }
  }

  const int orow = m_base + quad * 4;
#pragma unroll
  for (int nt = 0; nt < NT; ++nt) {
    int col = nt * 16 + r16;
    float bv = (col < ncols) ? bias[col] : 0.f;
#pragma unroll
    for (int r = 0; r < 4; ++r) {
      int grow = orow + r;
      if (grow < M && col < ncols) {
        float v = acc[nt][r] + bv;
        if (RELU) v = fmaxf(v, 0.f);
        if (OUTBF16)
          ((unsigned short*)out)[(size_t)grow * D + col] = (unsigned short)f2bf(v);
        else
          ((float*)out)[(size_t)grow * ncols + col] = v;
      }
    }
  }
}

// ---------------------------------------------------------------------------
extern "C" void kernel_launch(void* const* d_in, const int* in_sizes, int n_in,
                              void* d_out, int out_size, void* d_ws, size_t ws_size,
                              hipStream_t stream) {
  const float* x   = (const float*)d_in[0];
  const int*   src = (const int*)d_in[1];
  const int*   dst = (const int*)d_in[2];
  const float* W0  = (const float*)d_in[3];
  const float* b0  = (const float*)d_in[4];
  const float* W1  = (const float*)d_in[5];
  const float* b1  = (const float*)d_in[6];
  const float* W2  = (const float*)d_in[7];
  const float* b2  = (const float*)d_in[8];
  float* out = (float*)d_out;

  const int M = in_sizes[0] / D;  // 50000
  const int E = in_sizes[1];      // 600000

  // ws layout (16B-aligned chunks):
  // [xb bf16 M*128][t bf16 M*128][hb bf16 M*128][W0b][W1b][W2b 48x128]
  // [counts M][row_start M+4][col_idx E][partials 64]
  char* p = (char*)d_ws;
  unsigned short* xb = (unsigned short*)p;  p += (size_t)M * D * 2;
  unsigned short* t  = (unsigned short*)p;  p += (size_t)M * D * 2;
  unsigned short* hb = (unsigned short*)p;  p += (size_t)M * D * 2;
  unsigned short* W0b = (unsigned short*)p;  p += 128 * 128 * 2;
  unsigned short* W1b = (unsigned short*)p;  p += 128 * 128 * 2;
  unsigned short* W2b = (unsigned short*)p;  p += 48 * 128 * 2;
  int* counts    = (int*)p;  p += (size_t)M * 4;
  int* row_start = (int*)p;  p += (size_t)(M + 4) * 4;
  int* col_idx   = (int*)p;  p += (size_t)E * 4;
  int* partials  = (int*)p;

  const int n4 = M / 4;
  const int scanBlocks = (n4 + 255) / 256;
  const int edgeBlocks = (E + 255) / 256;
  const int gatherBlocks = (M * 64 + 255) / 256;  // 1 wave per node
  const int gemmBlocks = (M + 63) / 64;

  const int xConv4 = M * D / 4;
  const int nxb = (xConv4 + 255) / 256;
  const int nwb = (128 * 128 * 2 + 48 * 128 + 255) / 256;

  // --- Zero degree histogram, then fused convert+count ---
  hipMemsetAsync(counts, 0, (size_t)M * sizeof(int), stream);
  convert_count<<<nxb + nwb + edgeBlocks, 256, 0, stream>>>(
      (const float4*)x, (uint2*)xb, xConv4, nxb, W0, W1, W2, W0b, W1b, W2b,
      nwb, dst, counts, E);

  // --- CSR scan + fill ---
  scan_partA<<<scanBlocks, 256, 0, stream>>>(counts, partials, n4);
  scan_partB<<<1, 64, 0, stream>>>(partials, row_start, scanBlocks, M, E);
  scan_partC<<<scanBlocks, 256, 0, stream>>>(counts, partials, row_start, n4);
  fill_kernel<<<edgeBlocks, 256, 0, stream>>>(src, dst, counts, col_idx, E);

  // --- Layer 0 ---
  gather_bf16<<<gatherBlocks, 256, 0, stream>>>(
      (const unsigned*)xb, row_start, col_idx, (unsigned*)t, M);
  gemm_mfma<8, true, true><<<gemmBlocks, 256, 0, stream>>>(t, W0b, b0, hb, M, D);
  // --- Layer 1 ---
  gather_bf16<<<gatherBlocks, 256, 0, stream>>>(
      (const unsigned*)hb, row_start, col_idx, (unsigned*)t, M);
  gemm_mfma<8, true, true><<<gemmBlocks, 256, 0, stream>>>(t, W1b, b1, hb, M, D);
  // --- Layer 2 (fp32 out, no relu) ---
  gather_bf16<<<gatherBlocks, 256, 0, stream>>>(
      (const unsigned*)hb, row_start, col_idx, (unsigned*)t, M);
  gemm_mfma<3, false, false><<<gemmBlocks, 256, 0, stream>>>(t, W2b, b2, out, M, N_CLS);
}

// Round 12
// 284.352 us; speedup vs baseline: 1.0365x; 1.0365x over previous
//
#include <hip/hip_runtime.h>

#define D 128
#define N_CLS 40

// ---------------------------------------------------------------------------
// bf16 helpers (RNE)
// ---------------------------------------------------------------------------
__device__ __forceinline__ unsigned f2bf(float f) {
  unsigned u = __builtin_bit_cast(unsigned, f);
  u += 0x7fffu + ((u >> 16) & 1u);
  return u >> 16;
}
__device__ __forceinline__ float bf_lo(unsigned u) {
  return __builtin_bit_cast(float, u << 16);
}
__device__ __forceinline__ float bf_hi(unsigned u) {
  return __builtin_bit_cast(float, u & 0xffff0000u);
}

// ---------------------------------------------------------------------------
// Scan phase A: per-256-int4-block partial sums.
// ---------------------------------------------------------------------------
__global__ __launch_bounds__(256) void scan_partA(
    const int* __restrict__ counts, int* __restrict__ partials, int n4) {
  __shared__ int sh[256];
  const int tid = threadIdx.x;
  const int g = blockIdx.x * 256 + tid;
  int s = 0;
  if (g < n4) {
    const int4 c = reinterpret_cast<const int4*>(counts)[g];
    s = c.x + c.y + c.z + c.w;
  }
  sh[tid] = s;
  __syncthreads();
  for (int off = 128; off > 0; off >>= 1) {
    if (tid < off) sh[tid] += sh[tid + off];
    __syncthreads();
  }
  if (tid == 0) partials[blockIdx.x] = sh[0];
}

// ---------------------------------------------------------------------------
// Scan phase C (merged B+C): every block redundantly wave-scans the <=64
// partials, then does its local exclusive scan + offset. Writes row_start
// and counts (=cursor for fill). Block 0 writes row_start[M]=E.
// ---------------------------------------------------------------------------
__global__ __launch_bounds__(256) void scan_partC(
    int* __restrict__ counts, const int* __restrict__ partials,
    int* __restrict__ row_start, int n4, int nP, int M, int E) {
  __shared__ int sh[256];
  __shared__ int sp[64];
  const int tid = threadIdx.x;
  if (tid < 64) {
    int v = (tid < nP) ? partials[tid] : 0;
    int x = v;
#pragma unroll
    for (int off = 1; off < 64; off <<= 1) {
      int y = __shfl_up(x, off, 64);
      if (tid >= off) x += y;
    }
    sp[tid] = x - v;  // exclusive
  }
  __syncthreads();
  const int g = blockIdx.x * 256 + tid;
  int4 c = make_int4(0, 0, 0, 0);
  if (g < n4) c = reinterpret_cast<const int4*>(counts)[g];
  const int s0 = c.x, s1 = s0 + c.y, s2 = s1 + c.z, s3 = s2 + c.w;
  sh[tid] = s3;
  __syncthreads();
  for (int off = 1; off < 256; off <<= 1) {
    int y = (tid >= off) ? sh[tid - off] : 0;
    __syncthreads();
    sh[tid] += y;
    __syncthreads();
  }
  if (g < n4) {
    const int base = sp[blockIdx.x] + sh[tid] - s3;
    const int4 rs = make_int4(base, base + s0, base + s1, base + s2);
    reinterpret_cast<int4*>(row_start)[g] = rs;
    reinterpret_cast<int4*>(counts)[g] = rs;
  }
  if (blockIdx.x == 0 && tid == 0) row_start[M] = E;
}

__global__ __launch_bounds__(256) void fill_kernel(
    const int* __restrict__ src, const int* __restrict__ dst,
    int* __restrict__ cursor, int* __restrict__ col_idx, int n_edges) {
  int e = blockIdx.x * 256 + threadIdx.x;
  if (e < n_edges) {
    int p = atomicAdd(&cursor[dst[e]], 1);
    col_idx[p] = src[e];
  }
}

// ---------------------------------------------------------------------------
// Merged converter + degree count:
//   blocks [0, nxb):          x float4 -> packed bf16
//   blocks [nxb, nxb+nwb):    W0/W1/W2 -> bf16 (W2 padded to 48 rows)
//   blocks [nxb+nwb, ...):    counts[dst[e]]++  (edge histogram)
// ---------------------------------------------------------------------------
__global__ __launch_bounds__(256) void convert_count(
    const float4* __restrict__ x4, uint2* __restrict__ xb, int n4, int nxb,
    const float* __restrict__ W0, const float* __restrict__ W1,
    const float* __restrict__ W2, unsigned short* __restrict__ W0b,
    unsigned short* __restrict__ W1b, unsigned short* __restrict__ W2b,
    int nwb, const int* __restrict__ dst, int* __restrict__ counts,
    int n_edges) {
  if ((int)blockIdx.x < nxb) {
    int i = blockIdx.x * 256 + threadIdx.x;
    if (i < n4) {
      float4 v = x4[i];
      xb[i] = make_uint2(f2bf(v.x) | (f2bf(v.y) << 16),
                         f2bf(v.z) | (f2bf(v.w) << 16));
    }
  } else if ((int)blockIdx.x < nxb + nwb) {
    int idx = (blockIdx.x - nxb) * 256 + threadIdx.x;
    const int n0 = 128 * 128, n1 = 128 * 128, n2 = 48 * 128;
    if (idx < n0) {
      W0b[idx] = (unsigned short)f2bf(W0[idx]);
    } else if (idx < n0 + n1) {
      int i = idx - n0;
      W1b[i] = (unsigned short)f2bf(W1[i]);
    } else if (idx < n0 + n1 + n2) {
      int i = idx - n0 - n1;
      int r = i >> 7;
      W2b[i] = (r < N_CLS) ? (unsigned short)f2bf(W2[i]) : (unsigned short)0;
    }
  } else {
    int e = (blockIdx.x - nxb - nwb) * 256 + threadIdx.x;
    if (e < n_edges) atomicAdd(&counts[dst[e]], 1);
  }
}

// ---------------------------------------------------------------------------
// MFMA GEMM (raw, no bias): out[M, ncols](bf16) = A[M,128] @ B[NT*16,128]^T
// Block = 256 thr = 4 waves, 64 rows. A/B-frag: lane holds row (lane&15),
// k=(lane>>4)*8+j. C/D: col=lane&15, row=(lane>>4)*4+reg.
// ---------------------------------------------------------------------------
typedef __attribute__((ext_vector_type(8))) short bf16x8;
typedef __attribute__((ext_vector_type(4))) float f32x4;

template <int NT>
__global__ __launch_bounds__(256) void gemm_mfma(
    const unsigned short* __restrict__ A, const unsigned short* __restrict__ B,
    unsigned short* __restrict__ out, int M, int ncols, int ostride) {
  const int tid = threadIdx.x;
  const int wv = tid >> 6;
  const int lane = tid & 63;
  const int m_base = blockIdx.x * 64 + wv * 16;
  const int r16 = lane & 15;
  const int quad = lane >> 4;

  const short* Ap = (const short*)A + (size_t)(m_base + r16) * D + quad * 8;
  bf16x8 af[4];
#pragma unroll
  for (int ks = 0; ks < 4; ++ks)
    af[ks] = *reinterpret_cast<const bf16x8*>(Ap + ks * 32);

  f32x4 acc[NT];
#pragma unroll
  for (int nt = 0; nt < NT; ++nt) {
    acc[nt] = (f32x4){0.f, 0.f, 0.f, 0.f};
    const short* Bp = (const short*)B + (size_t)(nt * 16 + r16) * D + quad * 8;
#pragma unroll
    for (int ks = 0; ks < 4; ++ks) {
      bf16x8 bf = *reinterpret_cast<const bf16x8*>(Bp + ks * 32);
      acc[nt] = __builtin_amdgcn_mfma_f32_16x16x32_bf16(af[ks], bf, acc[nt], 0, 0, 0);
    }
  }

  const int orow = m_base + quad * 4;
#pragma unroll
  for (int nt = 0; nt < NT; ++nt) {
    int col = nt * 16 + r16;
#pragma unroll
    for (int r = 0; r < 4; ++r) {
      int grow = orow + r;
      if (grow < M && col < ncols)
        out[(size_t)grow * ostride + col] = (unsigned short)f2bf(acc[nt][r]);
    }
  }
}

// ---------------------------------------------------------------------------
// 128-wide gather (gemm-first): outb[n] = act(t[n] + sum_j t[col_j] + bias)
// One wave per node; coalesced index load + shfl broadcast; masked 16-wide
// rounds; fp32 accumulation; bias+relu fused.
// ---------------------------------------------------------------------------
template <bool RELU>
__global__ __launch_bounds__(256) void gather128(
    const unsigned* __restrict__ t, const int* __restrict__ row_start,
    const int* __restrict__ col_idx, const float* __restrict__ bias,
    unsigned* __restrict__ outb, int M) {
  const int wave = (blockIdx.x * 256 + threadIdx.x) >> 6;
  const int lane = threadIdx.x & 63;
  if (wave >= M) return;
  const float2 bb = reinterpret_cast<const float2*>(bias)[lane];
  const int s = row_start[wave];
  const int e = row_start[wave + 1];
  const int deg = e - s;
  unsigned su = t[(size_t)wave * 64 + lane];
  float ax[8], ay[8];
  ax[0] = bf_lo(su); ay[0] = bf_hi(su);
#pragma unroll
  for (int i = 1; i < 8; ++i) { ax[i] = 0.f; ay[i] = 0.f; }
  if (deg > 0) {
    const int cap = (deg < 64) ? deg : 64;
    const int ci = col_idx[s + ((lane < cap) ? lane : (cap - 1))];
    for (int base = 0; base < cap; base += 16) {
      unsigned v[16];
#pragma unroll
      for (int k = 0; k < 16; ++k) {
        int idx = base + k;
        int u = __shfl(ci, (idx < cap) ? idx : (cap - 1), 64);
        unsigned vv = t[(size_t)u * 64 + lane];
        v[k] = (idx < cap) ? vv : 0u;
      }
#pragma unroll
      for (int k = 0; k < 16; ++k) { ax[k & 7] += bf_lo(v[k]); ay[k & 7] += bf_hi(v[k]); }
    }
    for (int j = s + 64; j < e; ++j) {  // correctness-only tail
      unsigned v = t[(size_t)col_idx[j] * 64 + lane];
      ax[0] += bf_lo(v); ay[0] += bf_hi(v);
    }
  }
  float sx = (ax[0] + ax[1]) + (ax[2] + ax[3]) + ((ax[4] + ax[5]) + (ax[6] + ax[7])) + bb.x;
  float sy = (ay[0] + ay[1]) + (ay[2] + ay[3]) + ((ay[4] + ay[5]) + (ay[6] + ay[7])) + bb.y;
  if (RELU) { sx = fmaxf(sx, 0.f); sy = fmaxf(sy, 0.f); }
  outb[(size_t)wave * 64 + lane] = f2bf(sx) | (f2bf(sy) << 16);
}

// ---------------------------------------------------------------------------
// 40-wide final gather: out[n,0..39](fp32) = t2[n] + sum_j t2[col_j] + b2
// t2 is M x 40 bf16 (20 dwords/row, 4 MB -> L2-resident). Lanes 0..19 carry
// data; the coalesced index load + shfl uses all 64 lanes.
// ---------------------------------------------------------------------------
__global__ __launch_bounds__(256) void gather40(
    const unsigned* __restrict__ t2, const int* __restrict__ row_start,
    const int* __restrict__ col_idx, const float* __restrict__ b2,
    float* __restrict__ out, int M) {
  const int wave = (blockIdx.x * 256 + threadIdx.x) >> 6;
  const int lane = threadIdx.x & 63;
  if (wave >= M) return;
  const bool act = lane < 20;
  float2 bb = make_float2(0.f, 0.f);
  if (act) bb = reinterpret_cast<const float2*>(b2)[lane];
  const int s = row_start[wave];
  const int e = row_start[wave + 1];
  const int deg = e - s;
  float ax[4] = {0.f, 0.f, 0.f, 0.f}, ay[4] = {0.f, 0.f, 0.f, 0.f};
  if (act) {
    unsigned su = t2[(size_t)wave * 20 + lane];
    ax[0] = bf_lo(su); ay[0] = bf_hi(su);
  }
  if (deg > 0) {
    const int cap = (deg < 64) ? deg : 64;
    const int ci = col_idx[s + ((lane < cap) ? lane : (cap - 1))];
    for (int base = 0; base < cap; base += 8) {
      unsigned v[8];
#pragma unroll
      for (int k = 0; k < 8; ++k) {
        int idx = base + k;
        int u = __shfl(ci, (idx < cap) ? idx : (cap - 1), 64);
        v[k] = (act && idx < cap) ? t2[(size_t)u * 20 + lane] : 0u;
      }
#pragma unroll
      for (int k = 0; k < 8; ++k) { ax[k & 3] += bf_lo(v[k]); ay[k & 3] += bf_hi(v[k]); }
    }
    for (int j = s + 64; j < e; ++j) {  // correctness-only tail
      if (act) {
        unsigned v = t2[(size_t)col_idx[j] * 20 + lane];
        ax[0] += bf_lo(v); ay[0] += bf_hi(v);
      }
    }
  }
  if (act) {
    float sx = (ax[0] + ax[1]) + (ax[2] + ax[3]) + bb.x;
    float sy = (ay[0] + ay[1]) + (ay[2] + ay[3]) + bb.y;
    reinterpret_cast<float2*>(out + (size_t)wave * N_CLS)[lane] = make_float2(sx, sy);
  }
}

// ---------------------------------------------------------------------------
extern "C" void kernel_launch(void* const* d_in, const int* in_sizes, int n_in,
                              void* d_out, int out_size, void* d_ws, size_t ws_size,
                              hipStream_t stream) {
  const float* x   = (const float*)d_in[0];
  const int*   src = (const int*)d_in[1];
  const int*   dst = (const int*)d_in[2];
  const float* W0  = (const float*)d_in[3];
  const float* b0  = (const float*)d_in[4];
  const float* W1  = (const float*)d_in[5];
  const float* b1  = (const float*)d_in[6];
  const float* W2  = (const float*)d_in[7];
  const float* b2  = (const float*)d_in[8];
  float* out = (float*)d_out;

  const int M = in_sizes[0] / D;  // 50000
  const int E = in_sizes[1];      // 600000

  // ws layout (16B-aligned chunks):
  // [xb bf16 M*128][tA bf16 M*128][tB bf16 M*128][W0b][W1b][W2b 48x128]
  // [counts M][row_start M+4][col_idx E][partials 64]
  char* p = (char*)d_ws;
  unsigned short* xb = (unsigned short*)p;  p += (size_t)M * D * 2;
  unsigned short* tA = (unsigned short*)p;  p += (size_t)M * D * 2;
  unsigned short* tB = (unsigned short*)p;  p += (size_t)M * D * 2;
  unsigned short* W0b = (unsigned short*)p;  p += D * D * 2;
  unsigned short* W1b = (unsigned short*)p;  p += D * D * 2;
  unsigned short* W2b = (unsigned short*)p;  p += 48 * D * 2;
  int* counts    = (int*)p;  p += (size_t)M * 4;
  int* row_start = (int*)p;  p += (size_t)(M + 4) * 4;
  int* col_idx   = (int*)p;  p += (size_t)E * 4;
  int* partials  = (int*)p;

  const int n4 = M / 4;
  const int scanBlocks = (n4 + 255) / 256;       // 49
  const int edgeBlocks = (E + 255) / 256;
  const int gatherBlocks = (M * 64 + 255) / 256; // 1 wave per node
  const int gemmBlocks = (M + 63) / 64;

  const int xConv4 = M * D / 4;
  const int nxb = (xConv4 + 255) / 256;
  const int nwb = (128 * 128 * 2 + 48 * 128 + 255) / 256;

  // --- Zero histogram; fused convert+count ---
  hipMemsetAsync(counts, 0, (size_t)M * sizeof(int), stream);
  convert_count<<<nxb + nwb + edgeBlocks, 256, 0, stream>>>(
      (const float4*)x, (uint2*)xb, xConv4, nxb, W0, W1, W2, W0b, W1b, W2b,
      nwb, dst, counts, E);

  // --- CSR scan (A, merged B+C) + fill ---
  scan_partA<<<scanBlocks, 256, 0, stream>>>(counts, partials, n4);
  scan_partC<<<scanBlocks, 256, 0, stream>>>(counts, partials, row_start, n4,
                                             scanBlocks, M, E);
  fill_kernel<<<edgeBlocks, 256, 0, stream>>>(src, dst, counts, col_idx, E);

  // --- Layer 0: tA = xb@W0^T ; tB = relu(A·tA + b0) ---
  gemm_mfma<8><<<gemmBlocks, 256, 0, stream>>>(xb, W0b, tA, M, D, D);
  gather128<true><<<gatherBlocks, 256, 0, stream>>>(
      (const unsigned*)tA, row_start, col_idx, b0, (unsigned*)tB, M);

  // --- Layer 1: tA = tB@W1^T ; tB = relu(A·tA + b1) ---
  gemm_mfma<8><<<gemmBlocks, 256, 0, stream>>>(tB, W1b, tA, M, D, D);
  gather128<true><<<gatherBlocks, 256, 0, stream>>>(
      (const unsigned*)tA, row_start, col_idx, b1, (unsigned*)tB, M);

  // --- Layer 2: tA = tB@W2^T (M x 40 bf16) ; out = A·tA + b2 (fp32) ---
  gemm_mfma<3><<<gemmBlocks, 256, 0, stream>>>(tB, W2b, tA, M, N_CLS, N_CLS);
  gather40<<<gatherBlocks, 256, 0, stream>>>(
      (const unsigned*)tA, row_start, col_idx, b2, out, M);
}